// Round 14
// baseline (305.017 us; speedup 1.0000x reference)
//
#include <hip/hip_runtime.h>
#include <math.h>

#define SDIM 512
#define BDIM 64
#define HDIM 512
#define TDIM 32
#define MTOT (SDIM * BDIM)

typedef __attribute__((ext_vector_type(8))) short bf16x8;
typedef __attribute__((ext_vector_type(4))) float f32x4;

// static device scratch
__device__ unsigned short g_w1hT[HDIM * HDIM];        // W1^T hi [n][k]
__device__ unsigned short g_w1lT[HDIM * HDIM];        // W1^T lo [n][k]
__device__ unsigned short g_w2hT[TDIM * HDIM];        // W2^T hi [t][k]
__device__ unsigned short g_w2lT[TDIM * HDIM];        // W2^T lo [t][k]
__device__ unsigned short g_aH[(size_t)MTOT * HDIM];  // hidden hi [row][k] 33.5 MB
__device__ unsigned short g_aL[(size_t)MTOT * HDIM];  // hidden lo [row][k]
__device__ float g_em[(size_t)MTOT * TDIM];           // 4 MB emissions, b-major

__device__ __forceinline__ unsigned short f2bf(float x) {
  union { float f; unsigned int u; } v; v.f = x;
  unsigned int r = v.u + 0x7FFFu + ((v.u >> 16) & 1u);  // RNE
  return (unsigned short)(r >> 16);
}
__device__ __forceinline__ float bf2f(unsigned short h) {
  union { float f; unsigned int u; } v; v.u = ((unsigned int)h) << 16; return v.f;
}
__device__ __forceinline__ float fmax3(float a, float b, float c) {
  return fmaxf(fmaxf(a, b), c);  // fuses to v_max3_f32
}
__device__ __forceinline__ int imin3(int a, int b, int c) {
  int m = a < b ? a : b; return m < c ? m : c;  // fuses to v_min3_i32
}

// ---------------- W1/W2 split + transpose ----------------
__global__ void split_kernel(const float* __restrict__ W1, const float* __restrict__ W2) {
  const int n = blockIdx.x;
  const int k0 = threadIdx.x * 4;
  if (n < HDIM) {
    ushort4 h, l; float x;
    x = W1[(size_t)(k0 + 0) * HDIM + n]; h.x = f2bf(x); l.x = f2bf(x - bf2f(h.x));
    x = W1[(size_t)(k0 + 1) * HDIM + n]; h.y = f2bf(x); l.y = f2bf(x - bf2f(h.y));
    x = W1[(size_t)(k0 + 2) * HDIM + n]; h.z = f2bf(x); l.z = f2bf(x - bf2f(h.z));
    x = W1[(size_t)(k0 + 3) * HDIM + n]; h.w = f2bf(x); l.w = f2bf(x - bf2f(h.w));
    *(ushort4*)&g_w1hT[(size_t)n * HDIM + k0] = h;
    *(ushort4*)&g_w1lT[(size_t)n * HDIM + k0] = l;
  } else {
    const int t = n - HDIM;
    ushort4 h, l; float x;
    x = W2[(size_t)(k0 + 0) * TDIM + t]; h.x = f2bf(x); l.x = f2bf(x - bf2f(h.x));
    x = W2[(size_t)(k0 + 1) * TDIM + t]; h.y = f2bf(x); l.y = f2bf(x - bf2f(h.y));
    x = W2[(size_t)(k0 + 2) * TDIM + t]; h.z = f2bf(x); l.z = f2bf(x - bf2f(h.z));
    x = W2[(size_t)(k0 + 3) * TDIM + t]; h.w = f2bf(x); l.w = f2bf(x - bf2f(h.w));
    *(ushort4*)&g_w2hT[(size_t)t * HDIM + k0] = h;
    *(ushort4*)&g_w2lT[(size_t)t * HDIM + k0] = l;
  }
}

// ---------------- hidden split (memory-bound, one pass) ----------------
__global__ __launch_bounds__(256) void split_hidden(const float* __restrict__ hidden) {
  const size_t base = (size_t)blockIdx.x * 4096 + threadIdx.x * 4;
#pragma unroll
  for (int i = 0; i < 4; ++i) {
    size_t idx = base + (size_t)i * 1024;
    float4 v = *(const float4*)&hidden[idx];
    ushort4 h, l;
    h.x = f2bf(v.x); l.x = f2bf(v.x - bf2f(h.x));
    h.y = f2bf(v.y); l.y = f2bf(v.y - bf2f(h.y));
    h.z = f2bf(v.z); l.z = f2bf(v.z - bf2f(h.z));
    h.w = f2bf(v.w); l.w = f2bf(v.w - bf2f(h.w));
    *(ushort4*)&g_aH[idx] = h;
    *(ushort4*)&g_aL[idx] = l;
  }
}

// ---------------- Fused emissions (A pre-split -> light staging) ----------------
__global__ __launch_bounds__(256) void emis_kernel(
    const float* __restrict__ b1, const float* __restrict__ b2)
{
  __shared__ unsigned short lAh[64][40];
  __shared__ unsigned short lAl[64][40];
  __shared__ unsigned short lBh[128][40];
  __shared__ unsigned short lBl[128][40];
  __shared__ unsigned short H1h[64][136];
  __shared__ unsigned short H1l[64][136];

  const int tid = threadIdx.x;
  const int s = blockIdx.x;
  const int row0 = s * 64;
  const int wave = tid >> 6;
  const int lane = tid & 63;
  const int l15 = lane & 15;
  const int l4 = lane >> 4;
  const int wr1 = (wave >> 1) * 32;
  const int wc1 = (wave & 1) * 64;

  f32x4 acc_em[2];
  acc_em[0] = (f32x4)(0.f);
  acc_em[1] = (f32x4)(0.f);

  const int ar = tid >> 2, aq = tid & 3;  // A staging: 64 rows x 4 uint4

  for (int jcb = 0; jcb < 4; ++jcb) {
    const int jc = jcb * 128;

    f32x4 acc1[2][4];
#pragma unroll
    for (int i = 0; i < 2; ++i)
#pragma unroll
      for (int j = 0; j < 4; ++j) acc1[i][j] = (f32x4)(0.f);

    for (int k0 = 0; k0 < HDIM; k0 += 32) {
      // stage A from pre-split global (bf16 already)
      {
        const size_t ao = (size_t)(row0 + ar) * HDIM + k0 + 8 * aq;
        *(uint4*)&lAh[ar][8 * aq] = *(const uint4*)&g_aH[ao];
        *(uint4*)&lAl[ar][8 * aq] = *(const uint4*)&g_aL[ao];
      }
      // stage B from pre-split W1^T
#pragma unroll
      for (int i = 0; i < 2; ++i) {
        int f8 = tid + 256 * i;
        int nl = f8 >> 2, kq8 = f8 & 3;
        *(uint4*)&lBh[nl][8 * kq8] =
            *(const uint4*)&g_w1hT[(size_t)(jc + nl) * HDIM + k0 + 8 * kq8];
        *(uint4*)&lBl[nl][8 * kq8] =
            *(const uint4*)&g_w1lT[(size_t)(jc + nl) * HDIM + k0 + 8 * kq8];
      }
      __syncthreads();

      bf16x8 aH[2], aL[2];
#pragma unroll
      for (int i = 0; i < 2; ++i) {
        aH[i] = *(const bf16x8*)&lAh[wr1 + 16 * i + l15][8 * l4];
        aL[i] = *(const bf16x8*)&lAl[wr1 + 16 * i + l15][8 * l4];
      }
#pragma unroll
      for (int j = 0; j < 4; ++j) {
        bf16x8 bH = *(const bf16x8*)&lBh[wc1 + 16 * j + l15][8 * l4];
        bf16x8 bL = *(const bf16x8*)&lBl[wc1 + 16 * j + l15][8 * l4];
#pragma unroll
        for (int i = 0; i < 2; ++i) {
          acc1[i][j] = __builtin_amdgcn_mfma_f32_16x16x32_bf16(aH[i], bH, acc1[i][j], 0, 0, 0);
          acc1[i][j] = __builtin_amdgcn_mfma_f32_16x16x32_bf16(aH[i], bL, acc1[i][j], 0, 0, 0);
          acc1[i][j] = __builtin_amdgcn_mfma_f32_16x16x32_bf16(aL[i], bH, acc1[i][j], 0, 0, 0);
        }
      }
      __syncthreads();
    }

    // bias + sigmoid -> hi/lo bf16 into H1
#pragma unroll
    for (int j = 0; j < 4; ++j) {
      const int col = wc1 + 16 * j + l15;
      const float bv = b1[jc + col];
#pragma unroll
      for (int i = 0; i < 2; ++i) {
#pragma unroll
        for (int r = 0; r < 4; ++r) {
          int lrow = wr1 + 16 * i + 4 * l4 + r;
          float h = 1.f / (1.f + __expf(-(acc1[i][j][r] + bv)));
          unsigned short hh = f2bf(h);
          unsigned short hl = f2bf(h - bf2f(hh));
          H1h[lrow][col] = hh;
          H1l[lrow][col] = hl;
        }
      }
    }
    __syncthreads();

#pragma unroll
    for (int ks = 0; ks < 4; ++ks) {
      bf16x8 aH2 = *(const bf16x8*)&H1h[16 * wave + l15][32 * ks + 8 * l4];
      bf16x8 aL2 = *(const bf16x8*)&H1l[16 * wave + l15][32 * ks + 8 * l4];
#pragma unroll
      for (int j2 = 0; j2 < 2; ++j2) {
        const size_t wo = (size_t)(16 * j2 + l15) * HDIM + jc + 32 * ks + 8 * l4;
        bf16x8 bH2 = *(const bf16x8*)&g_w2hT[wo];
        bf16x8 bL2 = *(const bf16x8*)&g_w2lT[wo];
        acc_em[j2] = __builtin_amdgcn_mfma_f32_16x16x32_bf16(aH2, bH2, acc_em[j2], 0, 0, 0);
        acc_em[j2] = __builtin_amdgcn_mfma_f32_16x16x32_bf16(aH2, bL2, acc_em[j2], 0, 0, 0);
        acc_em[j2] = __builtin_amdgcn_mfma_f32_16x16x32_bf16(aL2, bH2, acc_em[j2], 0, 0, 0);
      }
    }
    __syncthreads();
  }

#pragma unroll
  for (int j2 = 0; j2 < 2; ++j2) {
    const int t = 16 * j2 + l15;
    const float bv = b2[t];
#pragma unroll
    for (int r = 0; r < 4; ++r) {
      int b = 16 * wave + 4 * l4 + r;
      g_em[((size_t)b * SDIM + s) * TDIM + t] = acc_em[j2][r] + bv;
    }
  }
}

// ---------------- Viterbi v8: LDS fv broadcast, full-32 per lane, no cross-lane ----------------
__global__ __launch_bounds__(64) void viterbi_kernel(
    const int* __restrict__ lens, const float* __restrict__ trans,
    float* __restrict__ out)
{
  __shared__ float fvL[64];
  __shared__ unsigned int bps32[SDIM / 4][TDIM];  // 16 KB
  const int b = blockIdx.x;
  const int lane = threadIdx.x;
  const int c = lane & 31;

  float tr[TDIM];
#pragma unroll
  for (int p = 0; p < TDIM; p += 4) {
    float4 t4 = *(const float4*)&trans[c * TDIM + p];
    tr[p] = t4.x; tr[p + 1] = t4.y; tr[p + 2] = t4.z; tr[p + 3] = t4.w;
  }

  int len;
  { const int* p32 = lens;
    len = (p32[1] == 0) ? (int)((const long long*)lens)[b] : p32[b]; }

  const float* emc = g_em + (size_t)b * SDIM * TDIM + c;

  float fvown = emc[0];  // t = 0 (lanes c and c+32 identical)
  fvL[lane] = fvown;

  // 12-deep register prefetch of em (t = 1..12)
  float ebuf[12];
#pragma unroll
  for (int j = 0; j < 12; ++j) ebuf[j] = emc[(size_t)(1 + j) * TDIM];

  unsigned int bpk = 0u;

  // one step: LDS broadcast read (same-addr, conflict-free), max3 tree value,
  // eq+min3 index (off critical path), branchless freeze
#define VSTEP(T, PH, EV)                                                       \
  {                                                                            \
    float4 q0 = *(const float4*)&fvL[0];                                       \
    float4 q1 = *(const float4*)&fvL[4];                                       \
    float4 q2 = *(const float4*)&fvL[8];                                       \
    float4 q3 = *(const float4*)&fvL[12];                                      \
    float4 q4 = *(const float4*)&fvL[16];                                      \
    float4 q5 = *(const float4*)&fvL[20];                                      \
    float4 q6 = *(const float4*)&fvL[24];                                      \
    float4 q7 = *(const float4*)&fvL[28];                                      \
    float sv[32];                                                              \
    sv[0] = q0.x + tr[0];  sv[1] = q0.y + tr[1];                               \
    sv[2] = q0.z + tr[2];  sv[3] = q0.w + tr[3];                               \
    sv[4] = q1.x + tr[4];  sv[5] = q1.y + tr[5];                               \
    sv[6] = q1.z + tr[6];  sv[7] = q1.w + tr[7];                               \
    sv[8] = q2.x + tr[8];  sv[9] = q2.y + tr[9];                               \
    sv[10] = q2.z + tr[10]; sv[11] = q2.w + tr[11];                            \
    sv[12] = q3.x + tr[12]; sv[13] = q3.y + tr[13];                            \
    sv[14] = q3.z + tr[14]; sv[15] = q3.w + tr[15];                            \
    sv[16] = q4.x + tr[16]; sv[17] = q4.y + tr[17];                            \
    sv[18] = q4.z + tr[18]; sv[19] = q4.w + tr[19];                            \
    sv[20] = q5.x + tr[20]; sv[21] = q5.y + tr[21];                            \
    sv[22] = q5.z + tr[22]; sv[23] = q5.w + tr[23];                            \
    sv[24] = q6.x + tr[24]; sv[25] = q6.y + tr[25];                            \
    sv[26] = q6.z + tr[26]; sv[27] = q6.w + tr[27];                            \
    sv[28] = q7.x + tr[28]; sv[29] = q7.y + tr[29];                            \
    sv[30] = q7.z + tr[30]; sv[31] = q7.w + tr[31];                            \
    float a0 = fmax3(sv[0], sv[1], sv[2]);                                     \
    float a1 = fmax3(sv[3], sv[4], sv[5]);                                     \
    float a2 = fmax3(sv[6], sv[7], sv[8]);                                     \
    float a3 = fmax3(sv[9], sv[10], sv[11]);                                   \
    float a4 = fmax3(sv[12], sv[13], sv[14]);                                  \
    float a5 = fmax3(sv[15], sv[16], sv[17]);                                  \
    float a6 = fmax3(sv[18], sv[19], sv[20]);                                  \
    float a7 = fmax3(sv[21], sv[22], sv[23]);                                  \
    float a8 = fmax3(sv[24], sv[25], sv[26]);                                  \
    float a9 = fmax3(sv[27], sv[28], sv[29]);                                  \
    float a10 = fmaxf(sv[30], sv[31]);                                         \
    float b0 = fmax3(a0, a1, a2);                                              \
    float b1_ = fmax3(a3, a4, a5);                                             \
    float b2_ = fmax3(a6, a7, a8);                                             \
    float b3_ = fmaxf(a9, a10);                                                \
    float m0 = fmaxf(fmaxf(b0, b1_), fmaxf(b2_, b3_));                         \
    const bool act = (T) < len;                                                \
    fvown = act ? (m0 + (EV)) : fvown;                                         \
    fvL[lane] = fvown;  /* next step's reads wait on this; index path hides */ \
    int i_[32];                                                                \
    _Pragma("unroll")                                                          \
    for (int j = 0; j < 32; ++j) i_[j] = (sv[j] == m0) ? j : 63;               \
    int u0 = imin3(i_[0], i_[1], i_[2]);                                       \
    int u1 = imin3(i_[3], i_[4], i_[5]);                                       \
    int u2 = imin3(i_[6], i_[7], i_[8]);                                       \
    int u3 = imin3(i_[9], i_[10], i_[11]);                                     \
    int u4 = imin3(i_[12], i_[13], i_[14]);                                    \
    int u5 = imin3(i_[15], i_[16], i_[17]);                                    \
    int u6 = imin3(i_[18], i_[19], i_[20]);                                    \
    int u7 = imin3(i_[21], i_[22], i_[23]);                                    \
    int u8 = imin3(i_[24], i_[25], i_[26]);                                    \
    int u9 = imin3(i_[27], i_[28], i_[29]);                                    \
    int ua = i_[30] < i_[31] ? i_[30] : i_[31];                                \
    int w0 = imin3(u0, u1, u2);                                                \
    int w1 = imin3(u3, u4, u5);                                                \
    int w2 = imin3(u6, u7, u8);                                                \
    int w3 = u9 < ua ? u9 : ua;                                                \
    int im = imin3(w0, w1, w2) < w3 ? imin3(w0, w1, w2) : w3;                  \
    int bp = act ? im : c;                                                     \
    bpk |= (unsigned)bp << (8 * (PH));                                         \
    if ((PH) == 3) { bps32[(T) >> 2][c] = bpk; bpk = 0u; }                     \
  }

#define LOADQ(BASE, T0)                                                        \
  {                                                                            \
    _Pragma("unroll")                                                          \
    for (int j = 0; j < 4; ++j) {                                              \
      int lt = (T0) + j; lt = lt > (SDIM - 1) ? (SDIM - 1) : lt;               \
      ebuf[(BASE) + j] = emc[(size_t)lt * TDIM];                               \
    }                                                                          \
  }

  {
    int tq = 1;
    for (; tq <= SDIM - 19; tq += 12) {  // t = 1..504
      VSTEP(tq + 0, 1, ebuf[0]) VSTEP(tq + 1, 2, ebuf[1])
      VSTEP(tq + 2, 3, ebuf[2]) VSTEP(tq + 3, 0, ebuf[3])
      LOADQ(0, tq + 12)
      VSTEP(tq + 4, 1, ebuf[4]) VSTEP(tq + 5, 2, ebuf[5])
      VSTEP(tq + 6, 3, ebuf[6]) VSTEP(tq + 7, 0, ebuf[7])
      LOADQ(4, tq + 16)
      VSTEP(tq + 8, 1, ebuf[8]) VSTEP(tq + 9, 2, ebuf[9])
      VSTEP(tq + 10, 3, ebuf[10]) VSTEP(tq + 11, 0, ebuf[11])
      LOADQ(8, tq + 20)
    }
    // tail: t = 505..511
    VSTEP(505, 1, ebuf[0]) VSTEP(506, 2, ebuf[1]) VSTEP(507, 3, ebuf[2])
    VSTEP(508, 0, ebuf[3]) VSTEP(509, 1, ebuf[4]) VSTEP(510, 2, ebuf[5])
    VSTEP(511, 3, ebuf[6])
  }
#undef VSTEP
#undef LOADQ

  // final argmax over tags (lowest index wins); fvown identical across halves
  float bs = fvown;
  int bi = c;
#pragma unroll
  for (int off = 16; off > 0; off >>= 1) {
    float os = __shfl_down(bs, off, 32);
    int oi = __shfl_down(bi, off, 32);
    if (os > bs || (os == bs && oi < bi)) { bs = os; bi = oi; }
  }
  bs = __shfl(bs, 0, 32);
  int tag = __shfl(bi, 0, 32);  // uniform

  out[(size_t)SDIM * BDIM + b] = bs;
  out[(size_t)(SDIM - 1) * BDIM + b] = (float)tag;

  // scalar backtrack via readlane over packed bps words
  unsigned bw_next = bps32[SDIM / 4 - 1][c];
  for (int w = SDIM / 4 - 1; w >= 0; --w) {
    unsigned bw = bw_next;
    if (w > 0) bw_next = bps32[w - 1][c];
#pragma unroll
    for (int j = 3; j >= 0; --j) {
      int t = 4 * w + j;
      if (t < 1) continue;
      unsigned word = (unsigned)__builtin_amdgcn_readlane((int)bw, tag);
      tag = (int)((word >> (8 * j)) & 255u);
      out[(size_t)(t - 1) * BDIM + b] = (float)tag;
    }
  }
}

// ---------------- host ----------------
static int find_by_size(const int* in_sizes, int n_in, int sz, int fb) {
  for (int i = 0; i < n_in; ++i) if (in_sizes[i] == sz) return i;
  return fb;
}

extern "C" void kernel_launch(void* const* d_in, const int* in_sizes, int n_in,
                              void* d_out, int out_size, void* d_ws, size_t ws_size,
                              hipStream_t stream) {
  const int i_hidden = find_by_size(in_sizes, n_in, SDIM * BDIM * HDIM, 0);
  const int i_lens   = find_by_size(in_sizes, n_in, BDIM, 1);
  const int i_W1     = find_by_size(in_sizes, n_in, HDIM * HDIM, 3);
  const int i_b1     = find_by_size(in_sizes, n_in, HDIM, 4);
  const int i_W2     = find_by_size(in_sizes, n_in, HDIM * TDIM, 5);
  const int i_b2     = find_by_size(in_sizes, n_in, TDIM, 6);
  const int i_tr     = find_by_size(in_sizes, n_in, TDIM * TDIM, 7);

  const float* hidden = (const float*)d_in[i_hidden];
  const int*   lens   = (const int*)d_in[i_lens];
  const float* W1     = (const float*)d_in[i_W1];
  const float* b1     = (const float*)d_in[i_b1];
  const float* W2     = (const float*)d_in[i_W2];
  const float* b2     = (const float*)d_in[i_b2];
  const float* trans  = (const float*)d_in[i_tr];
  float* out = (float*)d_out;

  split_kernel<<<HDIM + TDIM, 128, 0, stream>>>(W1, W2);
  split_hidden<<<(MTOT * HDIM) / 4096, 256, 0, stream>>>(hidden);
  emis_kernel<<<SDIM, 256, 0, stream>>>(b1, b2);
  viterbi_kernel<<<BDIM, 64, 0, stream>>>(lens, trans, out);
}

// Round 15
// 291.632 us; speedup vs baseline: 1.0459x; 1.0459x over previous
//
#include <hip/hip_runtime.h>
#include <math.h>

#define SDIM 512
#define BDIM 64
#define HDIM 512
#define TDIM 32
#define MTOT (SDIM * BDIM)

typedef __attribute__((ext_vector_type(8))) short bf16x8;
typedef __attribute__((ext_vector_type(4))) float f32x4;

// static device scratch
__device__ unsigned short g_w1hT[HDIM * HDIM];  // W1^T hi [n][k]
__device__ unsigned short g_w1lT[HDIM * HDIM];  // W1^T lo [n][k]
__device__ unsigned short g_w2hT[TDIM * HDIM];  // W2^T hi [t][k]
__device__ unsigned short g_w2lT[TDIM * HDIM];  // W2^T lo [t][k]
__device__ float g_em[(size_t)MTOT * TDIM];     // 4 MB emissions, b-major

__device__ __forceinline__ unsigned short f2bf(float x) {
  union { float f; unsigned int u; } v; v.f = x;
  unsigned int r = v.u + 0x7FFFu + ((v.u >> 16) & 1u);  // RNE
  return (unsigned short)(r >> 16);
}
__device__ __forceinline__ float bf2f(unsigned short h) {
  union { float f; unsigned int u; } v; v.u = ((unsigned int)h) << 16; return v.f;
}
__device__ __forceinline__ float fmax3(float a, float b, float c) {
  return fmaxf(fmaxf(a, b), c);  // fuses to v_max3_f32
}
__device__ __forceinline__ int imin3(int a, int b, int c) {
  int m = a < b ? a : b; return m < c ? m : c;  // fuses to v_min3_i32
}

// ---------------- W1/W2 split + transpose ----------------
__global__ void split_kernel(const float* __restrict__ W1, const float* __restrict__ W2) {
  const int n = blockIdx.x;
  const int k0 = threadIdx.x * 4;
  if (n < HDIM) {
    ushort4 h, l; float x;
    x = W1[(size_t)(k0 + 0) * HDIM + n]; h.x = f2bf(x); l.x = f2bf(x - bf2f(h.x));
    x = W1[(size_t)(k0 + 1) * HDIM + n]; h.y = f2bf(x); l.y = f2bf(x - bf2f(h.y));
    x = W1[(size_t)(k0 + 2) * HDIM + n]; h.z = f2bf(x); l.z = f2bf(x - bf2f(h.z));
    x = W1[(size_t)(k0 + 3) * HDIM + n]; h.w = f2bf(x); l.w = f2bf(x - bf2f(h.w));
    *(ushort4*)&g_w1hT[(size_t)n * HDIM + k0] = h;
    *(ushort4*)&g_w1lT[(size_t)n * HDIM + k0] = l;
  } else {
    const int t = n - HDIM;
    ushort4 h, l; float x;
    x = W2[(size_t)(k0 + 0) * TDIM + t]; h.x = f2bf(x); l.x = f2bf(x - bf2f(h.x));
    x = W2[(size_t)(k0 + 1) * TDIM + t]; h.y = f2bf(x); l.y = f2bf(x - bf2f(h.y));
    x = W2[(size_t)(k0 + 2) * TDIM + t]; h.z = f2bf(x); l.z = f2bf(x - bf2f(h.z));
    x = W2[(size_t)(k0 + 3) * TDIM + t]; h.w = f2bf(x); l.w = f2bf(x - bf2f(h.w));
    *(ushort4*)&g_w2hT[(size_t)t * HDIM + k0] = h;
    *(ushort4*)&g_w2lT[(size_t)t * HDIM + k0] = l;
  }
}

// ---------------- Fused emissions (r13 version, proven 124 us) ----------------
__global__ __launch_bounds__(256) void emis_kernel(
    const float* __restrict__ hidden, const float* __restrict__ b1,
    const float* __restrict__ b2)
{
  __shared__ unsigned short lAh[64][40];
  __shared__ unsigned short lAl[64][40];
  __shared__ unsigned short lBh[128][40];
  __shared__ unsigned short lBl[128][40];
  __shared__ unsigned short H1h[64][136];
  __shared__ unsigned short H1l[64][136];

  const int tid = threadIdx.x;
  const int s = blockIdx.x;
  const int row0 = s * 64;
  const int wave = tid >> 6;
  const int lane = tid & 63;
  const int l15 = lane & 15;
  const int l4 = lane >> 4;
  const int wr1 = (wave >> 1) * 32;
  const int wc1 = (wave & 1) * 64;

  f32x4 acc_em[2];
  acc_em[0] = (f32x4)(0.f);
  acc_em[1] = (f32x4)(0.f);

  for (int jcb = 0; jcb < 4; ++jcb) {
    const int jc = jcb * 128;

    f32x4 acc1[2][4];
#pragma unroll
    for (int i = 0; i < 2; ++i)
#pragma unroll
      for (int j = 0; j < 4; ++j) acc1[i][j] = (f32x4)(0.f);

    for (int k0 = 0; k0 < HDIM; k0 += 32) {
#pragma unroll
      for (int i = 0; i < 2; ++i) {
        int f4 = tid + 256 * i;
        int r = f4 >> 3, q = f4 & 7;
        float4 v = *(const float4*)&hidden[(size_t)(row0 + r) * HDIM + k0 + 4 * q];
        ushort4 h, l;
        h.x = f2bf(v.x); l.x = f2bf(v.x - bf2f(h.x));
        h.y = f2bf(v.y); l.y = f2bf(v.y - bf2f(h.y));
        h.z = f2bf(v.z); l.z = f2bf(v.z - bf2f(h.z));
        h.w = f2bf(v.w); l.w = f2bf(v.w - bf2f(h.w));
        *(ushort4*)&lAh[r][4 * q] = h;
        *(ushort4*)&lAl[r][4 * q] = l;
      }
#pragma unroll
      for (int i = 0; i < 2; ++i) {
        int f8 = tid + 256 * i;
        int nl = f8 >> 2, kq8 = f8 & 3;
        *(uint4*)&lBh[nl][8 * kq8] =
            *(const uint4*)&g_w1hT[(size_t)(jc + nl) * HDIM + k0 + 8 * kq8];
        *(uint4*)&lBl[nl][8 * kq8] =
            *(const uint4*)&g_w1lT[(size_t)(jc + nl) * HDIM + k0 + 8 * kq8];
      }
      __syncthreads();

      bf16x8 aH[2], aL[2];
#pragma unroll
      for (int i = 0; i < 2; ++i) {
        aH[i] = *(const bf16x8*)&lAh[wr1 + 16 * i + l15][8 * l4];
        aL[i] = *(const bf16x8*)&lAl[wr1 + 16 * i + l15][8 * l4];
      }
#pragma unroll
      for (int j = 0; j < 4; ++j) {
        bf16x8 bH = *(const bf16x8*)&lBh[wc1 + 16 * j + l15][8 * l4];
        bf16x8 bL = *(const bf16x8*)&lBl[wc1 + 16 * j + l15][8 * l4];
#pragma unroll
        for (int i = 0; i < 2; ++i) {
          acc1[i][j] = __builtin_amdgcn_mfma_f32_16x16x32_bf16(aH[i], bH, acc1[i][j], 0, 0, 0);
          acc1[i][j] = __builtin_amdgcn_mfma_f32_16x16x32_bf16(aH[i], bL, acc1[i][j], 0, 0, 0);
          acc1[i][j] = __builtin_amdgcn_mfma_f32_16x16x32_bf16(aL[i], bH, acc1[i][j], 0, 0, 0);
        }
      }
      __syncthreads();
    }

#pragma unroll
    for (int j = 0; j < 4; ++j) {
      const int col = wc1 + 16 * j + l15;
      const float bv = b1[jc + col];
#pragma unroll
      for (int i = 0; i < 2; ++i) {
#pragma unroll
        for (int r = 0; r < 4; ++r) {
          int lrow = wr1 + 16 * i + 4 * l4 + r;
          float h = 1.f / (1.f + __expf(-(acc1[i][j][r] + bv)));
          unsigned short hh = f2bf(h);
          unsigned short hl = f2bf(h - bf2f(hh));
          H1h[lrow][col] = hh;
          H1l[lrow][col] = hl;
        }
      }
    }
    __syncthreads();

#pragma unroll
    for (int ks = 0; ks < 4; ++ks) {
      bf16x8 aH2 = *(const bf16x8*)&H1h[16 * wave + l15][32 * ks + 8 * l4];
      bf16x8 aL2 = *(const bf16x8*)&H1l[16 * wave + l15][32 * ks + 8 * l4];
#pragma unroll
      for (int j2 = 0; j2 < 2; ++j2) {
        const size_t wo = (size_t)(16 * j2 + l15) * HDIM + jc + 32 * ks + 8 * l4;
        bf16x8 bH2 = *(const bf16x8*)&g_w2hT[wo];
        bf16x8 bL2 = *(const bf16x8*)&g_w2lT[wo];
        acc_em[j2] = __builtin_amdgcn_mfma_f32_16x16x32_bf16(aH2, bH2, acc_em[j2], 0, 0, 0);
        acc_em[j2] = __builtin_amdgcn_mfma_f32_16x16x32_bf16(aH2, bL2, acc_em[j2], 0, 0, 0);
        acc_em[j2] = __builtin_amdgcn_mfma_f32_16x16x32_bf16(aL2, bH2, acc_em[j2], 0, 0, 0);
      }
    }
    __syncthreads();
  }

#pragma unroll
  for (int j2 = 0; j2 < 2; ++j2) {
    const int t = 16 * j2 + l15;
    const float bv = b2[t];
#pragma unroll
    for (int r = 0; r < 4; ++r) {
      int b = 16 * wave + 4 * l4 + r;
      g_em[((size_t)b * SDIM + s) * TDIM + t] = acc_em[j2][r] + bv;
    }
  }
}

// ---------------- Viterbi v9: 2 chains/wave (de-duplicated v8) ----------------
__global__ __launch_bounds__(64) void viterbi_kernel(
    const int* __restrict__ lens, const float* __restrict__ trans,
    float* __restrict__ out)
{
  __shared__ float fvL[64];                     // [chain*32 + c]
  __shared__ unsigned int bps32[SDIM / 4][64];  // 32 KB, col = lane
  const int lane = threadIdx.x;
  const int c = lane & 31;
  const int h32 = lane & 32;       // chain offset in lanes
  const int b = 2 * blockIdx.x + (lane >> 5);

  float tr[TDIM];
#pragma unroll
  for (int p = 0; p < TDIM; p += 4) {
    float4 t4 = *(const float4*)&trans[c * TDIM + p];
    tr[p] = t4.x; tr[p + 1] = t4.y; tr[p + 2] = t4.z; tr[p + 3] = t4.w;
  }

  int len;
  { const int* p32 = lens;
    len = (p32[1] == 0) ? (int)((const long long*)lens)[b] : p32[b]; }

  const float* emc = g_em + (size_t)b * SDIM * TDIM + c;

  float fvown = emc[0];  // t = 0
  fvL[lane] = fvown;

  // 12-deep register prefetch of em (t = 1..12)
  float ebuf[12];
#pragma unroll
  for (int j = 0; j < 12; ++j) ebuf[j] = emc[(size_t)(1 + j) * TDIM];

  unsigned int bpk = 0u;
  const float* fvb = &fvL[h32];  // this chain's fv vector (broadcast reads)

#define VSTEP(T, PH, EV)                                                       \
  {                                                                            \
    float4 q0 = *(const float4*)(fvb + 0);                                     \
    float4 q1 = *(const float4*)(fvb + 4);                                     \
    float4 q2 = *(const float4*)(fvb + 8);                                     \
    float4 q3 = *(const float4*)(fvb + 12);                                    \
    float4 q4 = *(const float4*)(fvb + 16);                                    \
    float4 q5 = *(const float4*)(fvb + 20);                                    \
    float4 q6 = *(const float4*)(fvb + 24);                                    \
    float4 q7 = *(const float4*)(fvb + 28);                                    \
    float sv[32];                                                              \
    sv[0] = q0.x + tr[0];  sv[1] = q0.y + tr[1];                               \
    sv[2] = q0.z + tr[2];  sv[3] = q0.w + tr[3];                               \
    sv[4] = q1.x + tr[4];  sv[5] = q1.y + tr[5];                               \
    sv[6] = q1.z + tr[6];  sv[7] = q1.w + tr[7];                               \
    sv[8] = q2.x + tr[8];  sv[9] = q2.y + tr[9];                               \
    sv[10] = q2.z + tr[10]; sv[11] = q2.w + tr[11];                            \
    sv[12] = q3.x + tr[12]; sv[13] = q3.y + tr[13];                            \
    sv[14] = q3.z + tr[14]; sv[15] = q3.w + tr[15];                            \
    sv[16] = q4.x + tr[16]; sv[17] = q4.y + tr[17];                            \
    sv[18] = q4.z + tr[18]; sv[19] = q4.w + tr[19];                            \
    sv[20] = q5.x + tr[20]; sv[21] = q5.y + tr[21];                            \
    sv[22] = q5.z + tr[22]; sv[23] = q5.w + tr[23];                            \
    sv[24] = q6.x + tr[24]; sv[25] = q6.y + tr[25];                            \
    sv[26] = q6.z + tr[26]; sv[27] = q6.w + tr[27];                            \
    sv[28] = q7.x + tr[28]; sv[29] = q7.y + tr[29];                            \
    sv[30] = q7.z + tr[30]; sv[31] = q7.w + tr[31];                            \
    float a0 = fmax3(sv[0], sv[1], sv[2]);                                     \
    float a1 = fmax3(sv[3], sv[4], sv[5]);                                     \
    float a2 = fmax3(sv[6], sv[7], sv[8]);                                     \
    float a3 = fmax3(sv[9], sv[10], sv[11]);                                   \
    float a4 = fmax3(sv[12], sv[13], sv[14]);                                  \
    float a5 = fmax3(sv[15], sv[16], sv[17]);                                  \
    float a6 = fmax3(sv[18], sv[19], sv[20]);                                  \
    float a7 = fmax3(sv[21], sv[22], sv[23]);                                  \
    float a8 = fmax3(sv[24], sv[25], sv[26]);                                  \
    float a9 = fmax3(sv[27], sv[28], sv[29]);                                  \
    float a10 = fmaxf(sv[30], sv[31]);                                         \
    float b0 = fmax3(a0, a1, a2);                                              \
    float b1_ = fmax3(a3, a4, a5);                                             \
    float b2_ = fmax3(a6, a7, a8);                                             \
    float b3_ = fmaxf(a9, a10);                                                \
    float m0 = fmaxf(fmaxf(b0, b1_), fmaxf(b2_, b3_));                         \
    const bool act = (T) < len;                                                \
    fvown = act ? (m0 + (EV)) : fvown;                                         \
    fvL[lane] = fvown;                                                         \
    int i_[32];                                                                \
    _Pragma("unroll")                                                          \
    for (int j = 0; j < 32; ++j) i_[j] = (sv[j] == m0) ? j : 63;               \
    int u0 = imin3(i_[0], i_[1], i_[2]);                                       \
    int u1 = imin3(i_[3], i_[4], i_[5]);                                       \
    int u2 = imin3(i_[6], i_[7], i_[8]);                                       \
    int u3 = imin3(i_[9], i_[10], i_[11]);                                     \
    int u4 = imin3(i_[12], i_[13], i_[14]);                                    \
    int u5 = imin3(i_[15], i_[16], i_[17]);                                    \
    int u6 = imin3(i_[18], i_[19], i_[20]);                                    \
    int u7 = imin3(i_[21], i_[22], i_[23]);                                    \
    int u8 = imin3(i_[24], i_[25], i_[26]);                                    \
    int u9 = imin3(i_[27], i_[28], i_[29]);                                    \
    int ua = i_[30] < i_[31] ? i_[30] : i_[31];                                \
    int w0 = imin3(u0, u1, u2);                                                \
    int w1 = imin3(u3, u4, u5);                                                \
    int w2 = imin3(u6, u7, u8);                                                \
    int w3 = u9 < ua ? u9 : ua;                                                \
    int im = imin3(w0, w1, w2) < w3 ? imin3(w0, w1, w2) : w3;                  \
    int bp = act ? im : c;                                                     \
    bpk |= (unsigned)bp << (8 * (PH));                                         \
    if ((PH) == 3) { bps32[(T) >> 2][lane] = bpk; bpk = 0u; }                  \
  }

#define LOADQ(BASE, T0)                                                        \
  {                                                                            \
    _Pragma("unroll")                                                          \
    for (int j = 0; j < 4; ++j) {                                              \
      int lt = (T0) + j; lt = lt > (SDIM - 1) ? (SDIM - 1) : lt;               \
      ebuf[(BASE) + j] = emc[(size_t)lt * TDIM];                               \
    }                                                                          \
  }

  {
    int tq = 1;
    for (; tq <= SDIM - 19; tq += 12) {  // t = 1..504
      VSTEP(tq + 0, 1, ebuf[0]) VSTEP(tq + 1, 2, ebuf[1])
      VSTEP(tq + 2, 3, ebuf[2]) VSTEP(tq + 3, 0, ebuf[3])
      LOADQ(0, tq + 12)
      VSTEP(tq + 4, 1, ebuf[4]) VSTEP(tq + 5, 2, ebuf[5])
      VSTEP(tq + 6, 3, ebuf[6]) VSTEP(tq + 7, 0, ebuf[7])
      LOADQ(4, tq + 16)
      VSTEP(tq + 8, 1, ebuf[8]) VSTEP(tq + 9, 2, ebuf[9])
      VSTEP(tq + 10, 3, ebuf[10]) VSTEP(tq + 11, 0, ebuf[11])
      LOADQ(8, tq + 20)
    }
    // tail: t = 505..511
    VSTEP(505, 1, ebuf[0]) VSTEP(506, 2, ebuf[1]) VSTEP(507, 3, ebuf[2])
    VSTEP(508, 0, ebuf[3]) VSTEP(509, 1, ebuf[4]) VSTEP(510, 2, ebuf[5])
    VSTEP(511, 3, ebuf[6])
  }
#undef VSTEP
#undef LOADQ

  // per-half argmax over tags (width-32 keeps chains separate; lowest idx wins)
  float bs = fvown;
  int bi = c;
#pragma unroll
  for (int off = 16; off > 0; off >>= 1) {
    float os = __shfl_down(bs, off, 32);
    int oi = __shfl_down(bi, off, 32);
    if (os > bs || (os == bs && oi < bi)) { bs = os; bi = oi; }
  }
  bs = __shfl(bs, 0, 32);       // per-half broadcast
  int tag = __shfl(bi, 0, 32);  // per-half uniform

  if (c == 0) {
    out[(size_t)SDIM * BDIM + b] = bs;
    out[(size_t)(SDIM - 1) * BDIM + b] = (float)tag;
  }

  // backtrack both chains: word per 4 steps, 1 shfl per step
  unsigned bw_next = bps32[SDIM / 4 - 1][lane];
  for (int w = SDIM / 4 - 1; w >= 0; --w) {
    unsigned bw = bw_next;
    if (w > 0) bw_next = bps32[w - 1][lane];
#pragma unroll
    for (int j = 3; j >= 0; --j) {
      int t = 4 * w + j;
      if (t < 1) continue;
      unsigned word = (unsigned)__shfl((int)bw, h32 | tag, 64);
      tag = (int)((word >> (8 * j)) & 255u);
      if (c == 0) out[(size_t)(t - 1) * BDIM + b] = (float)tag;
    }
  }
}

// ---------------- host ----------------
static int find_by_size(const int* in_sizes, int n_in, int sz, int fb) {
  for (int i = 0; i < n_in; ++i) if (in_sizes[i] == sz) return i;
  return fb;
}

extern "C" void kernel_launch(void* const* d_in, const int* in_sizes, int n_in,
                              void* d_out, int out_size, void* d_ws, size_t ws_size,
                              hipStream_t stream) {
  const int i_hidden = find_by_size(in_sizes, n_in, SDIM * BDIM * HDIM, 0);
  const int i_lens   = find_by_size(in_sizes, n_in, BDIM, 1);
  const int i_W1     = find_by_size(in_sizes, n_in, HDIM * HDIM, 3);
  const int i_b1     = find_by_size(in_sizes, n_in, HDIM, 4);
  const int i_W2     = find_by_size(in_sizes, n_in, HDIM * TDIM, 5);
  const int i_b2     = find_by_size(in_sizes, n_in, TDIM, 6);
  const int i_tr     = find_by_size(in_sizes, n_in, TDIM * TDIM, 7);

  const float* hidden = (const float*)d_in[i_hidden];
  const int*   lens   = (const int*)d_in[i_lens];
  const float* W1     = (const float*)d_in[i_W1];
  const float* b1     = (const float*)d_in[i_b1];
  const float* W2     = (const float*)d_in[i_W2];
  const float* b2     = (const float*)d_in[i_b2];
  const float* trans  = (const float*)d_in[i_tr];
  float* out = (float*)d_out;

  split_kernel<<<HDIM + TDIM, 128, 0, stream>>>(W1, W2);
  emis_kernel<<<SDIM, 256, 0, stream>>>(hidden, b1, b2);
  viterbi_kernel<<<BDIM / 2, 64, 0, stream>>>(lens, trans, out);
}